// Round 8
// baseline (265.864 us; speedup 1.0000x reference)
//
#include <hip/hip_runtime.h>
#include <cstdint>

// ---------------- problem constants ----------------
#define NIMG  16
#define NCLS  80
#define HH    100
#define WW    152
#define HWSZ  (HH*WW)          // 15200
#define HW4   (HWSZ/4)         // 3800
#define NE    (HWSZ*NCLS)      // 1216000
#define KTOP  1000
#define POSTN 100
#define PRE_T 0.05f
#define NMS_T 0.6f
#define FLOOR_KEY 0x3D000000u
#define FLOOR_BIN 976
#define CAND_CAP  8192
#define SEL_CAP   2048
#define NTILE 240              // 64-elem chunks per class (238 real + 2 zero-padded)
#define NCHUNK (NCLS*NTILE)    // 19200 chunks per image
#define GRID_NB 256
#define DYN_LDS 136192         // bytes of dynamic LDS (scan phase: 1000*17*8 = 136000)

// ---------------- workspace layout (bytes) ----------------
#define OFF_HIST1 0u         // u32 [16][4096]  (zeroed in P0)
#define OFF_HIST2 262144u    // u32 [16][4096]  (zeroed in P0)
#define OFF_META  524288u    // u32 [16][16]    (zeroed in P0)
#define OFF_BAR   525312u    // u32 [32] barrier state (memset before launch)
#define OFF_CAND  525440u    // u64 [16][8192]
#define OFF_CMAX  1574016u   // u32 [16][19200]
#define OFF_BOX   2802816u   // f32 [16][1000][4]
#define OFF_OBOX  3058816u   // f32 [16][1000][4]
#define OFF_SC    3314816u   // f32 [16][1000]
#define OFF_LAB   3378816u   // i32 [16][1000]
#define OFF_MASK  3442816u   // u64 [16][1000][16]
#define OFF_COLS  5490816u   // u64 [16][16][64]

__device__ __forceinline__ float sigm(float x) { return 1.f / (1.f + expf(-x)); }

__device__ __forceinline__ uint64_t shfl64(uint64_t v, int src) {
  int lo = __shfl((int)(uint32_t)(v & 0xffffffffu), src, 64);
  int hi = __shfl((int)(uint32_t)(v >> 32), src, 64);
  return ((uint64_t)(uint32_t)hi << 32) | (uint32_t)lo;
}
__device__ __forceinline__ uint64_t shfl64x(uint64_t v, int d) {
  int lo = __shfl_xor((int)(uint32_t)(v & 0xffffffffu), d, 64);
  int hi = __shfl_xor((int)(uint32_t)(v >> 32), d, 64);
  return ((uint64_t)(uint32_t)hi << 32) | (uint32_t)lo;
}

// descending bitonic sort, thread-per-pair: one LDS round-trip per pass
__device__ __forceinline__ void bitonic_desc_tpp(uint64_t* s, int nn, int t, int nt) {
  const int np = nn >> 1;
  for (int k2 = 2; k2 <= nn; k2 <<= 1) {
    for (int j = k2 >> 1; j > 0; j >>= 1) {
      __syncthreads();
      for (int q = t; q < np; q += nt) {
        int i = ((q & ~(j - 1)) << 1) | (q & (j - 1));
        int p = i | j;
        uint64_t a = s[i], b = s[p];
        bool desc = ((i & k2) == 0);
        bool sw = desc ? (a < b) : (a > b);
        if (sw) { s[i] = b; s[p] = a; }
      }
    }
  }
  __syncthreads();
}

// device-scope grid barrier (sense via monotonically increasing generation)
__device__ __forceinline__ void grid_sync(unsigned* bar) {
  __syncthreads();
  if (threadIdx.x == 0) {
    __threadfence();                       // release prior writes (wb L2)
    unsigned my = atomicAdd(&bar[1], 0u);  // coherent read of generation
    __threadfence();                       // order: gen read strictly before arrive
    unsigned a = atomicAdd(&bar[0], 1u);
    if (a == GRID_NB - 1) {
      atomicExch(&bar[0], 0u);
      __threadfence();
      atomicAdd(&bar[1], 1u);
    } else {
      while (atomicAdd(&bar[1], 0u) == my) __builtin_amdgcn_s_sleep(2);
    }
    __threadfence();                       // acquire side (inv caches)
  }
  __syncthreads();
}

__global__ void __launch_bounds__(1024, 4) k_mega(
    const float4* __restrict__ cls4, const float* __restrict__ cls,
    const float4* __restrict__ ctr4, const float* __restrict__ ctr,
    const float* __restrict__ locations, const float* __restrict__ breg,
    const int* __restrict__ imsz,
    unsigned* zbase, unsigned* hist1, unsigned* hist2, unsigned* meta, unsigned* bar,
    uint64_t* cand, unsigned* cmax,
    float* boxes, float* obox, float* scw, int* labw,
    uint64_t* masks, uint64_t* colsg, float* out) {
  extern __shared__ char smem[];
  __shared__ uint64_t s_keepb[16];
  __shared__ int s_i[4];
  __shared__ unsigned s_u[4];
  const int b = blockIdx.x;
  const int t = threadIdx.x;
  const int lane = t & 63;
  const int wv = t >> 6;

  // ================= P0: zero hist1 + hist2 + meta (contiguous 131328 u32) =================
  {
    int gid = b * 1024 + t;
    if (gid < 131328) zbase[gid] = 0;
  }
  grid_sync(bar);

  // ================= P1: score histogram + per-chunk max keys =================
  {
    unsigned* h = (unsigned*)smem;                 // 4096 bins
    const int n = b >> 4, z = b & 15;              // 16 z-slices x 5 classes
    for (int i = t; i < 4096; i += 1024) h[i] = 0;
    __syncthreads();
    const float4* cp = cls4 + (size_t)n * (NE / 4);
    const float4* cr = ctr4 + (size_t)n * HW4;
    for (int c = z * 5; c < z * 5 + 5; ++c) {
#pragma unroll
      for (int it = 0; it < 4; ++it) {
        const int idx4 = it * 1024 + t;            // 0..4095
        unsigned k0 = 0, k1 = 0, k2 = 0, k3 = 0;
        if (idx4 < HW4) {
          float4 c4 = cr[idx4];
          float ct0 = sigm(c4.x), ct1 = sigm(c4.y), ct2 = sigm(c4.z), ct3 = sigm(c4.w);
          float4 v = cp[c * HW4 + idx4];
          float s0 = sigm(v.x), s1 = sigm(v.y), s2 = sigm(v.z), s3 = sigm(v.w);
          k0 = (s0 > PRE_T) ? __float_as_uint(s0 * ct0) : 0u;
          k1 = (s1 > PRE_T) ? __float_as_uint(s1 * ct1) : 0u;
          k2 = (s2 > PRE_T) ? __float_as_uint(s2 * ct2) : 0u;
          k3 = (s3 > PRE_T) ? __float_as_uint(s3 * ct3) : 0u;
          if (k0 >= FLOOR_KEY) atomicAdd(&h[k0 >> 20], 1u);
          if (k1 >= FLOOR_KEY) atomicAdd(&h[k1 >> 20], 1u);
          if (k2 >= FLOOR_KEY) atomicAdd(&h[k2 >> 20], 1u);
          if (k3 >= FLOOR_KEY) atomicAdd(&h[k3 >> 20], 1u);
        }
        unsigned km = max(max(k0, k1), max(k2, k3));
        km = max(km, (unsigned)__shfl_xor((int)km, 1, 64));
        km = max(km, (unsigned)__shfl_xor((int)km, 2, 64));
        km = max(km, (unsigned)__shfl_xor((int)km, 4, 64));
        km = max(km, (unsigned)__shfl_xor((int)km, 8, 64));
        const int tile = idx4 >> 4;
        if ((t & 15) == 0 && tile < NTILE)
          cmax[(size_t)n * NCHUNK + c * NTILE + tile] = km;
      }
    }
    __syncthreads();
    for (int i = t; i < 4096; i += 1024) {
      unsigned v = h[i];
      if (v) atomicAdd(&hist1[n * 4096 + i], v);
    }
  }
  grid_sync(bar);

  // ================= P2: per-block findbin + sparse collect (16 blocks/image) =================
  {
    const int n = b >> 4, slice = b & 15;
    unsigned* queue = (unsigned*)smem;             // up to 1200 entries
    unsigned* part = (unsigned*)(smem + 8192);     // 256 u32
    const unsigned* h1 = hist1 + n * 4096;
    if (t < 256) {
      unsigned ps = 0;
      for (int i = 0; i < 16; ++i) ps += h1[t * 16 + i];
      part[t] = ps;
    }
    if (t == 0) s_i[0] = 0;
    __syncthreads();
    if (t == 0) {
      unsigned cum = 0, cumAbove = 0;
      int bin = -1;
      for (int ch = 255; ch >= 0 && bin < 0; --ch) {
        if (cum + part[ch] >= (unsigned)KTOP) {
          for (int i = 15; i >= 0; --i) {
            unsigned v = h1[ch * 16 + i];
            if (cum + v >= (unsigned)KTOP) { bin = ch * 16 + i; cumAbove = cum; break; }
            cum += v;
          }
        } else cum += part[ch];
      }
      if (bin < 0) { bin = FLOOR_BIN; cumAbove = cum - h1[FLOOR_BIN]; }
      s_u[0] = (unsigned)bin;
      if (slice == 0) { meta[n * 16 + 0] = (unsigned)bin; meta[n * 16 + 1] = cumAbove; }
    }
    __syncthreads();
    const unsigned thr1 = s_u[0];
    const unsigned thrKey1 = thr1 << 20;
    const int c0 = slice * 1200;                   // NCHUNK/16 = 1200
    for (int i = t; i < 1200; i += 1024) {
      unsigned cm = cmax[(size_t)n * NCHUNK + c0 + i];
      if (cm >= thrKey1) { int p = atomicAdd(&s_i[0], 1); queue[p] = (unsigned)(c0 + i); }
    }
    __syncthreads();
    const int qn = s_i[0];
    for (int qi = wv; qi < qn; qi += 16) {
      int hc = (int)queue[qi];
      int c = hc / NTILE, tile = hc - c * NTILE;
      int hw = tile * 64 + lane;
      if (hw < HWSZ) {
        float s1 = sigm(cls[((size_t)n * NCLS + c) * HWSZ + hw]);
        float sc = sigm(ctr[(size_t)n * HWSZ + hw]);
        unsigned key = (s1 > PRE_T) ? __float_as_uint(s1 * sc) : 0u;
        if (key >= thrKey1) {
          unsigned fidx = (unsigned)(hw * NCLS + c);
          uint64_t comp = ((uint64_t)key << 21) | (uint64_t)(0x1FFFFFu - fidx);
          unsigned pos = atomicAdd(&meta[n * 16 + 2], 1u);
          if (pos < CAND_CAP) cand[(size_t)n * CAND_CAP + pos] = comp;
          if ((key >> 20) == thr1) atomicAdd(&hist2[n * 4096 + ((key >> 8) & 0xFFFu)], 1u);
        }
      }
    }
  }
  grid_sync(bar);

  // ================= P3: level-2 threshold, gather, sort, decode (16 blocks) =================
  if (b < NIMG) {
    const int n = b;
    uint64_t* sel = (uint64_t*)smem;               // 2048 u64 = 16 KB
    unsigned* part = (unsigned*)(smem + 16384);    // 256 u32
    const unsigned thr1 = meta[n * 16 + 0];
    const unsigned cumAbove = meta[n * 16 + 1];
    const int ccount = (int)min(meta[n * 16 + 2], (unsigned)CAND_CAP);
    const unsigned* h2 = hist2 + n * 4096;
    if (t < 256) {
      unsigned ps = 0;
      for (int i = 0; i < 16; ++i) ps += h2[t * 16 + i];
      part[t] = ps;
    }
    if (t == 0) s_i[1] = 0;
    __syncthreads();
    if (t == 0) {
      int need = (int)KTOP - (int)cumAbove;        // >= 1
      unsigned cum = 0;
      int b2 = -1;
      for (int ch = 255; ch >= 0 && b2 < 0; --ch) {
        if ((int)(cum + part[ch]) >= need) {
          for (int i = 15; i >= 0; --i) {
            unsigned v = h2[ch * 16 + i];
            if ((int)(cum + v) >= need) { b2 = ch * 16 + i; break; }
            cum += v;
          }
        } else cum += part[ch];
      }
      s_u[2] = (b2 < 0) ? (thr1 << 20) : ((thr1 << 20) | ((unsigned)b2 << 8));
    }
    __syncthreads();
    const unsigned thrKey2 = s_u[2];
    for (int j = t; j < ccount; j += 1024) {
      uint64_t comp = cand[(size_t)n * CAND_CAP + j];
      if ((unsigned)(comp >> 21) >= thrKey2) {
        int p = atomicAdd(&s_i[1], 1);
        if (p < SEL_CAP) sel[p] = comp;
      }
    }
    __syncthreads();
    const int m = min(s_i[1], SEL_CAP);
    for (int j = m + t; j < SEL_CAP; j += 1024) sel[j] = 0;
    __syncthreads();
    bitonic_desc_tpp(sel, SEL_CAP, t, 1024);
    const int nv = min(m, KTOP);
    if (t == 0) meta[n * 16 + 3] = (unsigned)nv;
    const float hi = (float)imsz[n * 2 + 0];
    const float wi = (float)imsz[n * 2 + 1];
    const float offmul = fmaxf(wi, hi) + 1.0f;
    for (int k = t; k < KTOP; k += 1024) {
      float x1 = 0, y1 = 0, x2 = 0, y2 = 0, ox1 = 0, oy1 = 0, ox2 = 0, oy2 = 0, s = 0;
      int lab = 0;
      if (k < nv) {
        uint64_t comp = sel[k];
        unsigned key = (unsigned)(comp >> 21);
        unsigned idx = 0x1FFFFFu - (unsigned)(comp & 0x1FFFFFu);
        int hw = (int)(idx / NCLS);
        int c  = (int)(idx - (unsigned)hw * NCLS);
        lab = c + 1;
        float lx = locations[hw * 2 + 0];
        float ly = locations[hw * 2 + 1];
        const float* rg = breg + (size_t)n * 4 * HWSZ;
        float rl = rg[hw], rt = rg[HWSZ + hw], rr = rg[2 * HWSZ + hw], rb = rg[3 * HWSZ + hw];
        x1 = fminf(fmaxf(lx - rl, 0.f), wi - 1.f);
        x2 = fminf(fmaxf(lx + rr, 0.f), wi - 1.f);
        y1 = fminf(fmaxf(ly - rt, 0.f), hi - 1.f);
        y2 = fminf(fmaxf(ly + rb, 0.f), hi - 1.f);
        float off = (float)lab * offmul;
        asm volatile("" : "+v"(off));      // keep the rounded off, forbid fma fusion
        ox1 = x1 + off; oy1 = y1 + off; ox2 = x2 + off; oy2 = y2 + off;
        s = sqrtf(__uint_as_float(key));
      }
      size_t bb = (size_t)(n * KTOP + k);
      boxes[bb * 4 + 0] = x1; boxes[bb * 4 + 1] = y1; boxes[bb * 4 + 2] = x2; boxes[bb * 4 + 3] = y2;
      obox[bb * 4 + 0] = ox1; obox[bb * 4 + 1] = oy1; obox[bb * 4 + 2] = ox2; obox[bb * 4 + 3] = oy2;
      scw[bb] = s;
      labw[bb] = lab;
    }
  }
  grid_sync(bar);

  // ================= P4: NMS adjacency bitmask + diagonal columns (16 blocks/image) =================
  {
    const int n = b >> 4, rg = b & 15;             // rows [rg*63, rg*63+63)
    const int nv = (int)meta[n * 16 + 3];
    float4* obs = (float4*)smem;                   // 16000 B
    float* ars = (float*)(smem + 16000);           // 4000 B
    const float4* ob = (const float4*)obox + (size_t)n * KTOP;
    for (int j = t; j < KTOP; j += 1024) {
      float4 bb = ob[j];
      obs[j] = bb;
      ars[j] = (bb.z - bb.x) * (bb.w - bb.y);      // LDS round-trip => rounded, no fusion across
    }
    __syncthreads();
    for (int rr = wv; rr < 63; rr += 16) {
      const int r = rg * 63 + rr;
      if (r >= nv) continue;                       // wave-uniform branch
      const float4 bi = obs[r];
      const float areai = ars[r];
      const int Wr = r >> 6;
      uint64_t* mr = masks + ((size_t)n * KTOP + r) * 16;
      for (int w = 0; w < 16; ++w) {
        int j = (w << 6) + lane;
        bool over = false;
        if (j < nv && j != r) {
          float4 bj = obs[j];
          float areaj = ars[j];
          float ltx = fmaxf(bi.x, bj.x), lty = fmaxf(bi.y, bj.y);
          float rbx = fminf(bi.z, bj.z), rby = fminf(bi.w, bj.w);
          float wx = fmaxf(rbx - ltx, 0.f), wy = fmaxf(rby - lty, 0.f);
          float inter = wx * wy;
          asm volatile("" : "+v"(inter));
          float denom = areai + areaj - inter + 1e-9f;
          over = (inter / denom) > NMS_T;
        }
        uint64_t bu = __ballot(over && (j > r));
        if (lane == 0) mr[w] = bu;
        if (w == Wr) {
          uint64_t bc = __ballot(over && (j < r));   // column via IoU symmetry
          if (lane == 0) colsg[((size_t)n * 16 + w) * 64 + (r & 63)] = bc;
        }
      }
    }
  }
  grid_sync(bar);

  // ================= P5: ballot fixed-point greedy scan + top-100 + output (16 blocks) ==========
  if (b < NIMG) {
    const int n = b;
    uint64_t* shmP = (uint64_t*)smem;              // [1000][17] padded = 136,000 B
    const int nv = (int)meta[n * 16 + 3];
    const ulonglong2* src = (const ulonglong2*)(masks + (size_t)n * KTOP * 16);
    for (int j2 = t; j2 < KTOP * 8; j2 += 1024) {
      ulonglong2 v = src[j2];
      int row = j2 >> 3, wp = (j2 & 7) << 1;
      shmP[row * 17 + wp] = v.x;
      shmP[row * 17 + wp + 1] = v.y;
    }
    __syncthreads();
    if (t < 64) {
      uint64_t colr[16];
#pragma unroll
      for (int W = 0; W < 16; ++W) colr[W] = colsg[((size_t)n * 16 + W) * 64 + lane];
      uint64_t rmv = 0;
      const uint64_t below = (lane == 0) ? 0ull : (~0ull >> (64 - lane));
#pragma unroll
      for (int W = 0; W < 16; ++W) {
        const int lo = W << 6;
        uint64_t cur0 = shfl64(rmv, W);
        if (nv <= lo) cur0 = ~0ull;
        else if (nv < lo + 64) cur0 |= (~0ull) << (nv - lo);
        uint64_t kept = ~cur0;
        for (int it = 0; it < 64; ++it) {
          bool pred = (((cur0 >> lane) & 1ull) == 0) && ((colr[W] & kept & below) == 0ull);
          uint64_t kn = __ballot(pred);
          if (kn == kept) break;
          kept = kn;
        }
        if (lane == 0) s_keepb[W] = kept;
        const int w = lane & 15, g = lane >> 4;
        uint64_t acc = 0;
#pragma unroll
        for (int i2 = 0; i2 < 16; ++i2) {
          const int i = (i2 << 2) + g;
          uint64_t msk = (uint64_t)0 - ((kept >> i) & 1ull);
          acc |= shmP[(lo + i) * 17 + w] & msk;
        }
        acc |= shfl64x(acc, 16);
        acc |= shfl64x(acc, 32);
        if (lane < 16) rmv |= acc;
      }
    }
    __syncthreads();
    uint64_t* sel = shmP;                          // reuse
    {
      const int k = t;
      uint64_t comp = 0;
      if (k < KTOP && ((s_keepb[k >> 6] >> (k & 63)) & 1ull)) {
        unsigned s = __float_as_uint(scw[(size_t)n * KTOP + k]);   // > 0 for kept
        comp = ((uint64_t)s << 10) | (uint64_t)(1023 - k);
      }
      sel[k] = comp;
    }
    __syncthreads();
    bitonic_desc_tpp(sel, 1024, t, 1024);
    if (t < POSTN) {
      const int k = t;
      uint64_t comp = sel[k];
      float x1 = 0, y1 = 0, x2 = 0, y2 = 0, fs = 0;
      int lab = 0;
      if (comp != 0) {
        int i = 1023 - (int)(comp & 0x3FFull);
        fs = __uint_as_float((unsigned)(comp >> 10));
        size_t bb = (size_t)(n * KTOP + i);
        x1 = boxes[bb * 4 + 0]; y1 = boxes[bb * 4 + 1];
        x2 = boxes[bb * 4 + 2]; y2 = boxes[bb * 4 + 3];
        lab = labw[bb];
      }
      float* dr = out + (size_t)(n * POSTN + k) * 5;
      dr[0] = x1; dr[1] = y1; dr[2] = x2; dr[3] = y2; dr[4] = fs;
      out[(size_t)NIMG * POSTN * 5 + (size_t)n * POSTN + k] = (float)lab;
    }
  }
}

extern "C" void kernel_launch(void* const* d_in, const int* in_sizes, int n_in,
                              void* d_out, int out_size, void* d_ws, size_t ws_size,
                              hipStream_t stream) {
  const float* locations = (const float*)d_in[0];
  const float* box_cls = (const float*)d_in[1];
  const float* box_reg = (const float*)d_in[2];
  const float* centerness = (const float*)d_in[3];
  const int* image_sizes = (const int*)d_in[4];
  char* ws = (char*)d_ws;

  unsigned* zbase = (unsigned*)(ws + OFF_HIST1);   // hist1+hist2+meta contiguous
  unsigned* hist1 = (unsigned*)(ws + OFF_HIST1);
  unsigned* hist2 = (unsigned*)(ws + OFF_HIST2);
  unsigned* meta = (unsigned*)(ws + OFF_META);
  unsigned* bar = (unsigned*)(ws + OFF_BAR);
  uint64_t* cand = (uint64_t*)(ws + OFF_CAND);
  unsigned* cmaxp = (unsigned*)(ws + OFF_CMAX);
  float* boxes = (float*)(ws + OFF_BOX);
  float* obox = (float*)(ws + OFF_OBOX);
  float* scw = (float*)(ws + OFF_SC);
  int* labw = (int*)(ws + OFF_LAB);
  uint64_t* masks = (uint64_t*)(ws + OFF_MASK);
  uint64_t* colsg = (uint64_t*)(ws + OFF_COLS);
  float* out = (float*)d_out;

  // barrier state must be zero at kernel start (ws is poisoned, not re-zeroed)
  hipMemsetAsync(ws + OFF_BAR, 0, 128, stream);

  k_mega<<<GRID_NB, 1024, DYN_LDS, stream>>>(
      (const float4*)box_cls, box_cls, (const float4*)centerness, centerness,
      locations, box_reg, image_sizes,
      zbase, hist1, hist2, meta, bar, cand, cmaxp,
      boxes, obox, scw, labw, masks, colsg, out);
}